// Round 9
// baseline (184.967 us; speedup 1.0000x reference)
//
#include <hip/hip_runtime.h>

#define L 4096
#define LMASK 4095
#define NCELL (L * L)

typedef float f32x2 __attribute__((ext_vector_type(2)));
typedef float f32x4 __attribute__((ext_vector_type(4)));
typedef int   i32x4 __attribute__((ext_vector_type(4)));

// greedy/tie flags from original q
#define QSEL(qv, Aj, gj, tj)                                   \
    {   const float qa0_ = (Aj) ? qv.z : qv.x;                 \
        const float qa1_ = (Aj) ? qv.w : qv.y;                 \
        gj = (qa1_ > qa0_) ? 1 : 0;                            \
        tj = (qa0_ == qa1_); }

// B select + Q[A][B] update (in place)
#define QUPD(qv, Aj, ej, rtj, profj, gj, Bj)                   \
    {   const int B_ = ((ej) >= 0.02f) ? (gj) : (rtj);         \
        const float mx_ = B_ ? fmaxf(qv.z, qv.w)               \
                             : fmaxf(qv.x, qv.y);              \
        const int ab_ = (Aj) * 2 + B_;                         \
        const float qab_ = (ab_ == 0) ? qv.x : (ab_ == 1) ? qv.y \
                         : (ab_ == 2) ? qv.z : qv.w;           \
        const float u_ = 0.2f * qab_ + 0.8f * ((profj) + 0.8f * mx_); \
        qv.x = (ab_ == 0) ? u_ : qv.x;                         \
        qv.y = (ab_ == 1) ? u_ : qv.y;                         \
        qv.z = (ab_ == 2) ? u_ : qv.z;                         \
        qv.w = (ab_ == 3) ? u_ : qv.w;                         \
        Bj = B_; }

__global__ __launch_bounds__(128) void spgg_qlearn_kernel(
    const int*   __restrict__ type_t,     // (L,L) int32, 0/1
    const f32x4* __restrict__ qtab,       // (N,2,2) f32
    const float* __restrict__ rnd,        // (N,2) f32 (tie-break only)
    const i32x4* __restrict__ rtype4,     // (L,L) int32, as quads
    const f32x4* __restrict__ eps4,       // (L,L) f32, as quads
    f32x4*       __restrict__ out_type4,  // (L,L) f32, as quads
    f32x4*       __restrict__ out_q,      // (N,2,2) f32
    f32x4*       __restrict__ out_prof4)  // (L,L) f32, as quads
{
    const i32x4* __restrict__ T4 = (const i32x4*)type_t;

    const int g  = blockIdx.x * 128 + threadIdx.x;  // quad index
    const int i0 = g << 2;                          // first cell (mult of 4)
    const int r  = i0 >> 12;
    const int c0 = i0 & LMASK;                      // multiple of 4

    // i32x4 row bases (quad units): row << 10; torus wrap
    const int R0  = r << 10;
    const int Rm1 = ((r - 1) & LMASK) << 10;
    const int Rp1 = ((r + 1) & LMASK) << 10;
    const int Rm2 = ((r - 2) & LMASK) << 10;
    const int Rp2 = ((r + 2) & LMASK) << 10;
    const int Pc  = c0 >> 2;
    const int Pm  = ((c0 - 4) & LMASK) >> 2;
    const int Pp  = ((c0 + 4) & LMASK) >> 2;

    // ---- 11 aligned int4 stencil loads, grouped for burst locality ----
    const i32x4 rA = T4[R0 + Pm],  rB = T4[R0 + Pc],  rC = T4[R0 + Pp];
    const i32x4 mA = T4[Rm1 + Pm], mB = T4[Rm1 + Pc], mC = T4[Rm1 + Pp];
    const i32x4 pA = T4[Rp1 + Pm], pB = T4[Rp1 + Pc], pC = T4[Rp1 + Pp];
    const i32x4 m2 = T4[Rm2 + Pc], p2 = T4[Rp2 + Pc];

    // q: each lane reads its own full 64B line (4 contiguous dwordx4)
    f32x4 q0 = qtab[i0];
    f32x4 q1 = qtab[i0 + 1];
    f32x4 q2 = qtab[i0 + 2];
    f32x4 q3 = qtab[i0 + 3];
    const f32x4 e4 = eps4[g];
    const i32x4 rt = rtype4[g];

    // cols as arrays offset +4 (constant indices after full unroll)
    const int rowr[12] = {rA.x,rA.y,rA.z,rA.w, rB.x,rB.y,rB.z,rB.w, rC.x,rC.y,rC.z,rC.w};
    const int rowm[12] = {mA.x,mA.y,mA.z,mA.w, mB.x,mB.y,mB.z,mB.w, mC.x,mC.y,mC.z,mC.w};
    const int rowp[12] = {pA.x,pA.y,pA.z,pA.w, pB.x,pB.y,pB.z,pB.w, pC.x,pC.y,pC.z,pC.w};
    const int rm2_[4]  = {m2.x, m2.y, m2.z, m2.w};
    const int rp2_[4]  = {p2.x, p2.y, p2.z, p2.w};

    // 13-point stencil == neigh5(neigh5(coop)), weights {5,2(cross),2(diag),1(far)}
    float prof[4];
    int   Aa[4];
    #pragma unroll
    for (int j = 0; j < 4; ++j) {
        const int jj = j + 4;
        const int self = rowr[jj];
        const int w = 5 * self
            + 2 * (rowr[jj-1] + rowr[jj+1] + rowm[jj] + rowp[jj]
                 + rowm[jj-1] + rowm[jj+1] + rowp[jj-1] + rowp[jj+1])
            + (rowr[jj-2] + rowr[jj+2] + rm2_[j] + rp2_[j]);
        prof[j] = 0.96f * (float)w - 5.0f * (float)self;  // (R/5)*W13 - 5*c
        Aa[j] = self;
    }

    int g0, g1, g2, g3;
    bool t0, t1, t2, t3;
    QSEL(q0, Aa[0], g0, t0)
    QSEL(q1, Aa[1], g1, t1)
    QSEL(q2, Aa[2], g2, t2)
    QSEL(q3, Aa[3], g3, t3)

    // Exact ties (~1 cell in 16.7M): wave-uniform scalar branch skips the
    // rnd loads entirely -> the 134 MB stream costs ~0 traffic, ~0 stalls.
    if (__any(t0 || t1 || t2 || t3)) {
        f32x2 v0, v1, v2, v3;
        asm volatile("global_load_dwordx2 %0, %4, off\n\t"
                     "global_load_dwordx2 %1, %5, off\n\t"
                     "global_load_dwordx2 %2, %6, off\n\t"
                     "global_load_dwordx2 %3, %7, off\n\t"
                     "s_waitcnt vmcnt(0)"
                     : "=v"(v0), "=v"(v1), "=v"(v2), "=v"(v3)
                     : "v"(rnd + 2 * (long)i0),     "v"(rnd + 2 * (long)i0 + 2),
                       "v"(rnd + 2 * (long)i0 + 4), "v"(rnd + 2 * (long)i0 + 6));
        if (t0) g0 = (v0.y > v0.x) ? 1 : 0;
        if (t1) g1 = (v1.y > v1.x) ? 1 : 0;
        if (t2) g2 = (v2.y > v2.x) ? 1 : 0;
        if (t3) g3 = (v3.y > v3.x) ? 1 : 0;
    }

    int B0, B1, B2, B3;
    QUPD(q0, Aa[0], e4.x, rt.x, prof[0], g0, B0)
    QUPD(q1, Aa[1], e4.y, rt.y, prof[1], g1, B1)
    QUPD(q2, Aa[2], e4.z, rt.z, prof[2], g2, B2)
    QUPD(q3, Aa[3], e4.w, rt.w, prof[3], g3, B3)

    // ---- grouped coalesced stores (64B/lane q, 16B/lane others) ----
    f32x4 ot; ot.x = (float)B0; ot.y = (float)B1; ot.z = (float)B2; ot.w = (float)B3;
    f32x4 pf; pf.x = prof[0];   pf.y = prof[1];   pf.z = prof[2];   pf.w = prof[3];
    out_q[i0]     = q0;
    out_q[i0 + 1] = q1;
    out_q[i0 + 2] = q2;
    out_q[i0 + 3] = q3;
    out_type4[g]  = ot;
    out_prof4[g]  = pf;
}

extern "C" void kernel_launch(void* const* d_in, const int* in_sizes, int n_in,
                              void* d_out, int out_size, void* d_ws, size_t ws_size,
                              hipStream_t stream) {
    const int*   type_t = (const int*)d_in[0];
    const f32x4* qtab   = (const f32x4*)d_in[1];
    const float* rnd    = (const float*)d_in[2];
    const i32x4* rtype4 = (const i32x4*)d_in[3];
    const f32x4* eps4   = (const f32x4*)d_in[4];

    float* out       = (float*)d_out;
    f32x4* o_type4   = (f32x4*)out;                        // N
    f32x4* o_q       = (f32x4*)(out + NCELL);              // 4N
    f32x4* o_prof4   = (f32x4*)(out + 5 * (size_t)NCELL);  // N

    // 4 cells/thread, 128-thread blocks: 512 cells/block -> 8 blocks/row,
    // so vertical neighbors (b +/- 8) stay on the SAME XCD (8 % 8 == 0).
    spgg_qlearn_kernel<<<NCELL / 512, 128, 0, stream>>>(
        type_t, qtab, rnd, rtype4, eps4, o_type4, o_q, o_prof4);
}

// Round 10
// 154.826 us; speedup vs baseline: 1.1947x; 1.1947x over previous
//
#include <hip/hip_runtime.h>

#define L 4096
#define LMASK 4095
#define NCELL (L * L)

typedef float f32x2 __attribute__((ext_vector_type(2)));
typedef float f32x4 __attribute__((ext_vector_type(4)));

__global__ __launch_bounds__(256) void spgg_qlearn_kernel(
    const int*    __restrict__ type_t,     // (L,L) int32, 0/1
    const f32x4*  __restrict__ qtab,       // (N,2,2) f32 -> vec4 per cell
    const float*  __restrict__ rnd,        // (N,2) f32 (tie-break only)
    const int*    __restrict__ rtype,      // (L,L) int32 0/1 (explore only)
    const float*  __restrict__ eps,        // (L,L) f32
    float*        __restrict__ out_type,   // (L,L) f32
    f32x4*        __restrict__ out_q,      // (N,2,2) f32
    float*        __restrict__ out_profit) // (L,L) f32
{
    const int i = blockIdx.x * 256 + threadIdx.x;   // < 2^24
    const int r = i >> 12;
    const int c = i & LMASK;

    // Row bases (element index), torus wrap
    const int r0  = r << 12;
    const int rm1 = ((r - 1) & LMASK) << 12;
    const int rp1 = ((r + 1) & LMASK) << 12;
    const int rm2 = ((r - 2) & LMASK) << 12;
    const int rp2 = ((r + 2) & LMASK) << 12;
    const int cm1 = (c - 1) & LMASK;
    const int cp1 = (c + 1) & LMASK;
    const int cm2 = (c - 2) & LMASK;
    const int cp2 = (c + 2) & LMASK;

    // ---- type stencil loads first (13), then streaming loads: the
    // compiler's waitcnt staging lets stencil math start while q/eps are
    // still in flight. All independent -> max MLP.
    const int t00 = type_t[r0 + c];
    const int f1  = type_t[rm2 + c];        // far (weight 1)
    const int f2  = type_t[rp2 + c];
    const int f3  = type_t[r0 + cm2];
    const int f4  = type_t[r0 + cp2];
    const int x1  = type_t[rm1 + c];        // cross (weight 2)
    const int x2  = type_t[rp1 + c];
    const int x3  = type_t[r0 + cm1];
    const int x4  = type_t[r0 + cp1];
    const int g1  = type_t[rm1 + cm1];      // diag (weight 2)
    const int g2  = type_t[rm1 + cp1];
    const int g3  = type_t[rp1 + cm1];
    const int g4  = type_t[rp1 + cp1];

    f32x4 q = qtab[i];                      // [0][0],[0][1],[1][0],[1][1]
    const float e = eps[i];

    // 13-point stencil == neigh5(neigh5(coop)), weights {5,2(cross),2(diag),1(far)}
    const int w13 = 5 * t00 + 2 * (x1 + x2 + x3 + x4) + 2 * (g1 + g2 + g3 + g4)
                  + (f1 + f2 + f3 + f4);

    // profit = (R/5)*W13 - 5*c    (R/5 = 0.96)
    const float profit = 0.96f * (float)w13 - 5.0f * (float)t00;

    const int A = t00;
    const float qa0 = A ? q.z : q.x;
    const float qa1 = A ? q.w : q.y;

    // Non-tie greedy decided by q alone (argmax over masked+rand).
    int greedy = (qa1 > qa0) ? 1 : 0;

    // Exact ties (~few cells in 16.7M): wave-uniform scalar branch skips
    // the rnd load entirely -> 134 MB stream costs ~0 traffic, ~0 stalls.
    if (__any(qa0 == qa1)) {
        f32x2 rv;
        asm volatile("global_load_dwordx2 %0, %1, off\n\t"
                     "s_waitcnt vmcnt(0)"
                     : "=v"(rv) : "v"(rnd + 2 * (long)i));
        if (qa0 == qa1) greedy = (rv.y > rv.x) ? 1 : 0;
    }

    // Exploration (2% of lanes): wave-uniform skip — ~27% of waves have no
    // exploring lane and skip the rtype line fetch entirely (~18 MB saved).
    int B = greedy;
    if (__any(e < 0.02f)) {
        const int rt = rtype[i];            // regular load, exec-masked wave branch
        if (e < 0.02f) B = rt;
    }

    // max_a' Q[B][a'] from the ORIGINAL table
    const float maxv = B ? fmaxf(q.z, q.w) : fmaxf(q.x, q.y);

    // Q[A][B] <- (1-eta)*Q[A][B] + eta*(profit + gamma*maxv)
    const int ab = A * 2 + B;
    const float qab = (ab == 0) ? q.x : (ab == 1) ? q.y : (ab == 2) ? q.z : q.w;
    const float upd = 0.2f * qab + 0.8f * (profit + 0.8f * maxv);

    q.x = (ab == 0) ? upd : q.x;
    q.y = (ab == 1) ? upd : q.y;
    q.z = (ab == 2) ? upd : q.z;
    q.w = (ab == 3) ? upd : q.w;

    out_type[i]   = (float)B;
    out_q[i]      = q;
    out_profit[i] = profit;
}

extern "C" void kernel_launch(void* const* d_in, const int* in_sizes, int n_in,
                              void* d_out, int out_size, void* d_ws, size_t ws_size,
                              hipStream_t stream) {
    const int*    type_t = (const int*)d_in[0];
    const f32x4*  qtab   = (const f32x4*)d_in[1];
    const float*  rnd    = (const float*)d_in[2];
    const int*    rtype  = (const int*)d_in[3];
    const float*  eps    = (const float*)d_in[4];

    float* out    = (float*)d_out;
    float* o_type = out;                          // N
    f32x4* o_q    = (f32x4*)(out + NCELL);        // 4N
    float* o_prof = out + 5 * (size_t)NCELL;      // N

    // 1 cell/thread, unit-stride everything (best measured structure).
    // 16 blocks/row, 16 % 8 == 0 -> vertical-neighbor blocks same XCD.
    spgg_qlearn_kernel<<<NCELL / 256, 256, 0, stream>>>(
        type_t, qtab, rnd, rtype, eps, o_type, o_q, o_prof);
}

// Round 11
// 143.107 us; speedup vs baseline: 1.2925x; 1.0819x over previous
//
#include <hip/hip_runtime.h>

#define L 4096
#define LMASK 4095
#define NCELL (L * L)

typedef float f32x2 __attribute__((ext_vector_type(2)));
typedef float f32x4 __attribute__((ext_vector_type(4)));

__global__ __launch_bounds__(256) void spgg_qlearn_kernel(
    const int*    __restrict__ type_t,     // (L,L) int32, 0/1 (REUSED -> cached)
    const f32x4*  __restrict__ qtab,       // (N,2,2) f32 (single-use -> NT)
    const float*  __restrict__ rnd,        // (N,2) f32 (tie-break only)
    const int*    __restrict__ rtype,      // (L,L) int32 (explore only)
    const float*  __restrict__ eps,        // (L,L) f32 (single-use -> NT)
    float*        __restrict__ out_type,   // (L,L) f32
    f32x4*        __restrict__ out_q,      // (N,2,2) f32
    float*        __restrict__ out_profit) // (L,L) f32
{
    const int i = blockIdx.x * 256 + threadIdx.x;   // < 2^24
    const int r = i >> 12;
    const int c = i & LMASK;

    // Row bases (element index), torus wrap
    const int r0  = r << 12;
    const int rm1 = ((r - 1) & LMASK) << 12;
    const int rp1 = ((r + 1) & LMASK) << 12;
    const int rm2 = ((r - 2) & LMASK) << 12;
    const int rp2 = ((r + 2) & LMASK) << 12;
    const int cm1 = (c - 1) & LMASK;
    const int cp1 = (c + 1) & LMASK;
    const int cm2 = (c - 2) & LMASK;
    const int cp2 = (c + 2) & LMASK;

    // ---- type stencil loads first (13, cached — 13x reuse), then the
    // streaming loads. All independent -> max MLP.
    const int t00 = type_t[r0 + c];
    const int f1  = type_t[rm2 + c];        // far (weight 1)
    const int f2  = type_t[rp2 + c];
    const int f3  = type_t[r0 + cm2];
    const int f4  = type_t[r0 + cp2];
    const int x1  = type_t[rm1 + c];        // cross (weight 2)
    const int x2  = type_t[rp1 + c];
    const int x3  = type_t[r0 + cm1];
    const int x4  = type_t[r0 + cp1];
    const int g1  = type_t[rm1 + cm1];      // diag (weight 2)
    const int g2  = type_t[rm1 + cp1];
    const int g3  = type_t[rp1 + cm1];
    const int g4  = type_t[rp1 + cp1];

    // Zero-reuse streams, full-line-per-instruction (1-cell/thread layout):
    // nontemporal -> no L2 allocate, L2 stays reserved for the type stencil.
    f32x4 q = __builtin_nontemporal_load(&qtab[i]);
    const float e = __builtin_nontemporal_load(&eps[i]);

    // 13-point stencil == neigh5(neigh5(coop)), weights {5,2(cross),2(diag),1(far)}
    const int w13 = 5 * t00 + 2 * (x1 + x2 + x3 + x4) + 2 * (g1 + g2 + g3 + g4)
                  + (f1 + f2 + f3 + f4);

    // profit = (R/5)*W13 - 5*c    (R/5 = 0.96)
    const float profit = 0.96f * (float)w13 - 5.0f * (float)t00;

    const int A = t00;
    const float qa0 = A ? q.z : q.x;
    const float qa1 = A ? q.w : q.y;

    // Non-tie greedy decided by q alone (argmax over masked+rand).
    int greedy = (qa1 > qa0) ? 1 : 0;

    // Exact ties (~few cells in 16.7M): wave-uniform scalar branch skips
    // the rnd load entirely -> 134 MB stream costs ~0 traffic, ~0 stalls.
    if (__any(qa0 == qa1)) {
        f32x2 rv;
        asm volatile("global_load_dwordx2 %0, %1, off\n\t"
                     "s_waitcnt vmcnt(0)"
                     : "=v"(rv) : "v"(rnd + 2 * (long)i));
        if (qa0 == qa1) greedy = (rv.y > rv.x) ? 1 : 0;
    }

    // Exploration (2% of lanes): wave-uniform skip — ~27% of waves have no
    // exploring lane and skip the rtype line fetch entirely.
    int B = greedy;
    if (__any(e < 0.02f)) {
        const int rt = __builtin_nontemporal_load(&rtype[i]);
        if (e < 0.02f) B = rt;
    }

    // max_a' Q[B][a'] from the ORIGINAL table
    const float maxv = B ? fmaxf(q.z, q.w) : fmaxf(q.x, q.y);

    // Q[A][B] <- (1-eta)*Q[A][B] + eta*(profit + gamma*maxv)
    const int ab = A * 2 + B;
    const float qab = (ab == 0) ? q.x : (ab == 1) ? q.y : (ab == 2) ? q.z : q.w;
    const float upd = 0.2f * qab + 0.8f * (profit + 0.8f * maxv);

    q.x = (ab == 0) ? upd : q.x;
    q.y = (ab == 1) ? upd : q.y;
    q.z = (ab == 2) ? upd : q.z;
    q.w = (ab == 3) ? upd : q.w;

    // Nontemporal streaming stores (full-line-per-instruction patterns).
    __builtin_nontemporal_store((float)B, &out_type[i]);
    __builtin_nontemporal_store(q, &out_q[i]);
    __builtin_nontemporal_store(profit, &out_profit[i]);
}

extern "C" void kernel_launch(void* const* d_in, const int* in_sizes, int n_in,
                              void* d_out, int out_size, void* d_ws, size_t ws_size,
                              hipStream_t stream) {
    const int*    type_t = (const int*)d_in[0];
    const f32x4*  qtab   = (const f32x4*)d_in[1];
    const float*  rnd    = (const float*)d_in[2];
    const int*    rtype  = (const int*)d_in[3];
    const float*  eps    = (const float*)d_in[4];

    float* out    = (float*)d_out;
    float* o_type = out;                          // N
    f32x4* o_q    = (f32x4*)(out + NCELL);        // 4N
    float* o_prof = out + 5 * (size_t)NCELL;      // N

    // 1 cell/thread, unit-stride everything (best measured structure).
    // 16 blocks/row, 16 % 8 == 0 -> vertical-neighbor blocks same XCD.
    spgg_qlearn_kernel<<<NCELL / 256, 256, 0, stream>>>(
        type_t, qtab, rnd, rtype, eps, o_type, o_q, o_prof);
}